// Round 9
// baseline (363.642 us; speedup 1.0000x reference)
//
#include <hip/hip_runtime.h>
#include <cstdint>
#include <cstddef>

#define DIN 1280
#define DOUT 3840
#define NEXP 6
#define RANK 16
#define TOKENS 16384
#define KPAD 1408   // 1280 x + 16 shared + 96 routed + 16 zero pad
#define NLOW 128    // padded low-rank cols (112 valid)

typedef __bf16 bf16x8 __attribute__((ext_vector_type(8)));
typedef float f32x4 __attribute__((ext_vector_type(4)));
typedef unsigned short u16x8 __attribute__((ext_vector_type(8)));

__device__ __forceinline__ unsigned short f2bf(float f) {
    unsigned u = __builtin_bit_cast(unsigned, f);
    u += 0x7fff + ((u >> 16) & 1);   // RNE
    return (unsigned short)(u >> 16);
}

__device__ __forceinline__ void async_load16(void* lds, const void* g) {
    __builtin_amdgcn_global_load_lds(
        (const __attribute__((address_space(1))) unsigned int*)g,
        (__attribute__((address_space(3))) unsigned int*)lds, 16, 0, 0);
}

// Build WcatT [DOUT][KPAD] bf16: rows n, cols k. k<1280: base_w[k][n];
// 1280..1295: shared_w2[k-1280][n]; 1296..1391: routed_w2 flat[k-1296][n]; else 0.
__global__ void prep_w2t(const float* __restrict__ base_w,
                         const float* __restrict__ shared_w2,
                         const float* __restrict__ routed_w2,
                         unsigned short* __restrict__ WT) {
    __shared__ unsigned short tile[32][33];
    int k0 = blockIdx.x * 32, n0 = blockIdx.y * 32;
    int tx = threadIdx.x, ty = threadIdx.y;
#pragma unroll
    for (int j = 0; j < 4; j++) {
        int k = k0 + ty + j * 8;
        int n = n0 + tx;
        float v;
        if (k < DIN)            v = base_w[(size_t)k * DOUT + n];
        else if (k < DIN + 16)  v = shared_w2[(size_t)(k - DIN) * DOUT + n];
        else if (k < DIN + 112) v = routed_w2[(size_t)(k - DIN - 16) * DOUT + n];
        else                    v = 0.f;
        tile[ty + j * 8][tx] = f2bf(v);
    }
    __syncthreads();
#pragma unroll
    for (int j = 0; j < 4; j++) {
        int n = n0 + ty + j * 8;
        int k = k0 + tx;
        WT[(size_t)n * KPAD + k] = tile[tx][ty + j * 8];
    }
}

// Build W1catT [NLOW][DIN] bf16: row n<16: shared_w1[:,n]; 16..111: routed_w1[e][:,r]; else 0.
__global__ void prep_w1t(const float* __restrict__ shared_w1,
                         const float* __restrict__ routed_w1,
                         unsigned short* __restrict__ W1T) {
    __shared__ unsigned short tile[32][33];
    int k0 = blockIdx.x * 32, n0 = blockIdx.y * 32;
    int tx = threadIdx.x, ty = threadIdx.y;
#pragma unroll
    for (int j = 0; j < 4; j++) {
        int k = k0 + ty + j * 8;
        int n = n0 + tx;
        float v = 0.f;
        if (n < 16) v = shared_w1[k * RANK + n];
        else if (n < 112) {
            int jj = n - 16, e = jj >> 4, r = jj & 15;
            v = routed_w1[(size_t)e * DIN * RANK + k * RANK + r];
        }
        tile[ty + j * 8][tx] = f2bf(v);
    }
    __syncthreads();
#pragma unroll
    for (int j = 0; j < 4; j++) {
        int n = n0 + ty + j * 8;
        int k = k0 + tx;
        W1T[(size_t)n * DIN + k] = tile[tx][ty + j * 8];
    }
}

// Fused single-pass router: each 8-f32 chunk of x is loaded ONCE, converted to
// bf16 into A[:,0:1280] AND accumulated into the 6 router logits (saves the old
// second 84 MB scalar read of x). 32 lanes per token; shuffle-reduce; softmax;
// top-3 -> cw[T,6]. Also zeros A[:,1392:1408].
__global__ __launch_bounds__(256) void router_kernel(
    const float* __restrict__ x,
    const float* __restrict__ router_w,
    const float* __restrict__ router_b,
    unsigned short* __restrict__ A,
    float* __restrict__ cw) {
    int tid = threadIdx.x;
    size_t t0 = (size_t)blockIdx.x * 8;
    int tg = tid >> 5, lj = tid & 31;
    const float* xt = x + (t0 + tg) * DIN;
    unsigned short* At = A + (t0 + tg) * KPAD;

    float acc[6] = {0.f, 0.f, 0.f, 0.f, 0.f, 0.f};
#pragma unroll
    for (int cc = 0; cc < 5; cc++) {          // 160 chunks / 32 lanes = 5 each
        int c = (lj + cc * 32) * 8;
        f32x4 v0 = *(const f32x4*)(xt + c);
        f32x4 v1 = *(const f32x4*)(xt + c + 4);
        u16x8 o;
#pragma unroll
        for (int j = 0; j < 4; j++) { o[j] = f2bf(v0[j]); o[4 + j] = f2bf(v1[j]); }
        *(u16x8*)&At[c] = o;
        const float* rw = router_w + (size_t)c * NEXP;
#pragma unroll
        for (int j = 0; j < 8; j++) {
            float xv = (j < 4) ? v0[j] : v1[j - 4];
#pragma unroll
            for (int e = 0; e < NEXP; e++)
                acc[e] = fmaf(xv, rw[j * NEXP + e], acc[e]);
        }
    }
    if (tid < 128) {
        int t = tid >> 4, cz = tid & 15;
        A[(t0 + t) * KPAD + DIN + 112 + cz] = 0;
    }

#pragma unroll
    for (int off = 16; off > 0; off >>= 1)
#pragma unroll
        for (int e = 0; e < NEXP; e++) acc[e] += __shfl_xor(acc[e], off);

    float mx = -1e30f;
#pragma unroll
    for (int e = 0; e < NEXP; e++) { acc[e] += router_b[e]; mx = fmaxf(mx, acc[e]); }
    float g[6]; float s = 0.f;
#pragma unroll
    for (int e = 0; e < NEXP; e++) { g[e] = __expf(acc[e] - mx); s += g[e]; }
    float inv = 1.f / s;
    if (lj < NEXP) {
        float ge = g[lj];
        int cnt = 0;
#pragma unroll
        for (int e = 0; e < NEXP; e++) {
            if (e == lj) continue;
            if (g[e] > ge || (g[e] == ge && e < lj)) cnt++;  // tie -> lowest index wins
        }
        cw[(t0 + tg) * NEXP + lj] = (cnt < 3) ? ge * inv : 0.f;
    }
}

// A[t, 1280+j] = bf16( (j<16 ? 1 : cw[t][(j-16)/16]) * (H0+H1)[t][j] ), j in [0,112)
__global__ __launch_bounds__(256) void combine_kernel(
    const float* __restrict__ H, const float* __restrict__ cw,
    unsigned short* __restrict__ A) {
    int i = blockIdx.x * 256 + threadIdx.x;  // < TOKENS*112
    int t = i / 112, j = i - t * 112;
    float h = H[(size_t)t * NLOW + j] + H[(size_t)TOKENS * NLOW + (size_t)t * NLOW + j];
    float f = (j < 16) ? 1.0f : cw[t * NEXP + ((j - 16) >> 4)];
    A[(size_t)t * KPAD + DIN + j] = f2bf(f * h);
}

// Small GEMM H[z][m,n] = A[m, z*640 : z*640+640] @ W1T[n, z*640 : ...]^T.
__global__ __launch_bounds__(256, 2) void gemm_small(
    const unsigned short* __restrict__ A,
    const unsigned short* __restrict__ BT,
    float* __restrict__ H) {
    __shared__ unsigned short ldsA[128 * 32];
    __shared__ unsigned short ldsB[128 * 32];
    const int KS = DIN / 2;  // 640
    int tid = threadIdx.x;
    int lane = tid & 63, wave = tid >> 6;
    int m0 = blockIdx.y * 128;
    int z = blockIdx.z;
    int wm = (wave >> 1) * 64, wn = (wave & 1) * 64;
    int lr = lane & 15, quad = lane >> 4;

    f32x4 acc[4][4] = {};
    const unsigned short* Abase = A + (size_t)m0 * KPAD + z * KS;
    const unsigned short* Bbase = BT + z * KS;
    float* Cbase = H + (size_t)z * TOKENS * NLOW;

    for (int k0 = 0; k0 < KS; k0 += 32) {
#pragma unroll
        for (int i = 0; i < 2; i++) {
            int c = i * 256 + tid;
            int row = c >> 2;
            int col = (c & 3) << 3;
            async_load16(&ldsA[(i * 256 + wave * 64) * 8],
                         Abase + (size_t)row * KPAD + k0 + col);
            async_load16(&ldsB[(i * 256 + wave * 64) * 8],
                         Bbase + (size_t)row * DIN + k0 + col);
        }
        __syncthreads();
        bf16x8 af[4], bf[4];
#pragma unroll
        for (int mi = 0; mi < 4; mi++)
            af[mi] = *(const bf16x8*)&ldsA[(wm + mi * 16 + lr) * 32 + quad * 8];
#pragma unroll
        for (int ni = 0; ni < 4; ni++)
            bf[ni] = *(const bf16x8*)&ldsB[(wn + ni * 16 + lr) * 32 + quad * 8];
#pragma unroll
        for (int mi = 0; mi < 4; mi++)
#pragma unroll
            for (int ni = 0; ni < 4; ni++)
                acc[mi][ni] = __builtin_amdgcn_mfma_f32_16x16x32_bf16(
                    af[mi], bf[ni], acc[mi][ni], 0, 0, 0);
        __syncthreads();
    }
#pragma unroll
    for (int ni = 0; ni < 4; ni++) {
        int gn = wn + ni * 16 + lr;
#pragma unroll
        for (int mi = 0; mi < 4; mi++) {
            int gm = m0 + wm + mi * 16 + quad * 4;
            f32x4 v = acc[mi][ni];
#pragma unroll
            for (int r = 0; r < 4; r++)
                Cbase[(size_t)(gm + r) * NLOW + gn] = v[r];
        }
    }
}

// ---------- big GEMM: 256x256, BK=64, A via LDS dbuf, B DIRECT global->VGPR ----------
// R4-R8 verdict: no explicit schedule makes LDS-fed operands overlap MFMA (5 schedules
// = 32-36%; skeleton w/o LDS = 84.5%). So: remove B from LDS. WcatT panel (0.72 MB,
// shared by the XCD's 8 blocks via swizzle) is L2-resident; B-frags load straight to
// VGPRs (16 rows x one 64B line, quads cover the 4 chunks -> fully coalesced),
// double-set, prefetched 1 tile ahead. A keeps gload_lds double-buffer. NO sched
// pins, NO manual waitcnt: plain __syncthreads once per tile (its vmcnt(0) drain is
// free -- all outstanding ops were issued a full tile earlier). Compiler does m97-
// style counted-lgkm quad pipelining on the A reads.

#define NKT 22   // K-tiles of 64

#define GTILE(CUR, BRC, BRN) do { \
    const int t_ = 2 * tt + (CUR); \
    if (t_ + 1 < NKT) { stA(&lA[(CUR) ^ 1][0], (t_ + 1) * 64); ldB(BRN, t_ + 1); } \
    const unsigned short* a_cur = &lA[CUR][0]; \
    _Pragma("unroll") \
    for (int q = 0; q < 4; q++) { \
        bf16x8 a00 = rdA(a_cur, q * 2 + 0, 0), a01 = rdA(a_cur, q * 2 + 0, 1); \
        bf16x8 a10 = rdA(a_cur, q * 2 + 1, 0), a11 = rdA(a_cur, q * 2 + 1, 1); \
        _Pragma("unroll") \
        for (int ni = 0; ni < 4; ni++) { \
            acc[q * 2 + 0][ni] = __builtin_amdgcn_mfma_f32_16x16x32_bf16( \
                a00, BRC[ni * 2 + 0], acc[q * 2 + 0][ni], 0, 0, 0); \
            acc[q * 2 + 0][ni] = __builtin_amdgcn_mfma_f32_16x16x32_bf16( \
                a01, BRC[ni * 2 + 1], acc[q * 2 + 0][ni], 0, 0, 0); \
            acc[q * 2 + 1][ni] = __builtin_amdgcn_mfma_f32_16x16x32_bf16( \
                a10, BRC[ni * 2 + 0], acc[q * 2 + 1][ni], 0, 0, 0); \
            acc[q * 2 + 1][ni] = __builtin_amdgcn_mfma_f32_16x16x32_bf16( \
                a11, BRC[ni * 2 + 1], acc[q * 2 + 1][ni], 0, 0, 0); \
        } \
    } \
    __syncthreads(); \
} while (0)

__global__ __launch_bounds__(512, 2) void gemm256(
    const unsigned short* __restrict__ A,
    const unsigned short* __restrict__ BT,
    const float* __restrict__ bias,
    float* __restrict__ C) {
    __shared__ unsigned short lA[2][256 * 64];   // 64 KB total

    int tid = threadIdx.x;
    int lane = tid & 63, wave = tid >> 6;
    int bid = blockIdx.x;
    // XCD swizzle (960 % 8 == 0, bijective): XCD x owns m-tiles [8x, 8x+8);
    // the 8 co-resident blocks share one 0.72 MB B-panel -> B is L2-resident.
    int xcd = bid & 7, lid = bid >> 3;
    int mt = xcd * 8 + (lid & 7);   // 0..63
    int nt = lid >> 3;              // 0..14
    int m0 = mt * 256, n0 = nt * 256;

    int wm = (wave >> 2) * 128, wn = (wave & 3) * 64;   // 2M x 4N waves, 128x64 each
    int lr = lane & 15, quad = lane >> 4;
    int swz = (lr & 7) << 4;

    // A staging (proven involution): lane l writes LDS chunk l%8 of row l/8;
    // source pre-swizzled chunk (l%8)^(l/8); reads XOR with (lr&7).
    int sr = lane >> 3;
    int sc = (lane & 7) ^ sr;
    const unsigned short* aSrc = A + (size_t)(m0 + wave * 32 + sr) * KPAD + sc * 8;
    // B direct: lane reads BT[n0 + wn + ni*16 + lr][t*64 + ks*32 + quad*8 ..+8].
    const unsigned short* bPtr = BT + (size_t)(n0 + wn + lr) * KPAD + quad * 8;

    auto stA = [&](unsigned short* dst, int k0) {
#pragma unroll
        for (int i = 0; i < 4; i++)
            async_load16(dst + (size_t)(wave * 32 + i * 8) * 64,
                         aSrc + (size_t)(i * 8) * KPAD + k0);
    };
    auto rdA = [&](const unsigned short* base, int mi, int ks) -> bf16x8 {
        int row = wm + mi * 16 + lr;
        int off = row * 128 + (((ks << 6) | (quad << 4)) ^ swz);
        return *(const bf16x8*)((const char*)base + off);
    };
    auto ldB = [&](bf16x8* dst, int t) {
#pragma unroll
        for (int ni = 0; ni < 4; ni++)
#pragma unroll
            for (int ks = 0; ks < 2; ks++)
                dst[ni * 2 + ks] = *(const bf16x8*)(
                    bPtr + (size_t)(ni * 16) * KPAD + t * 64 + ks * 32);
    };

    f32x4 acc[8][4] = {};
    bf16x8 br0[8], br1[8];

    // Prologue: A(0) -> buf0, B(0) -> set0; full drain (one-time cost).
    stA(&lA[0][0], 0);
    ldB(br0, 0);
    __syncthreads();

    for (int tt = 0; tt < NKT / 2; ++tt) {
        GTILE(0, br0, br1);
        GTILE(1, br1, br0);
    }

    // Epilogue: C/D layout col = lane&15, row = quad*4 + reg (verified mapping)
#pragma unroll
    for (int mi = 0; mi < 8; mi++) {
        int gm = m0 + wm + mi * 16 + quad * 4;
#pragma unroll
        for (int ni = 0; ni < 4; ni++) {
            int gn = n0 + wn + ni * 16 + lr;
            float bv = bias[gn];
            f32x4 v = acc[mi][ni];
#pragma unroll
            for (int r = 0; r < 4; r++)
                C[(size_t)(gm + r) * DOUT + gn] = v[r] + bv;
        }
    }
}

extern "C" void kernel_launch(void* const* d_in, const int* in_sizes, int n_in,
                              void* d_out, int out_size, void* d_ws, size_t ws_size,
                              hipStream_t stream) {
    const float* x         = (const float*)d_in[0];
    const float* base_w    = (const float*)d_in[1];
    const float* base_b    = (const float*)d_in[2];
    const float* shared_w1 = (const float*)d_in[3];
    const float* shared_w2 = (const float*)d_in[4];
    const float* routed_w1 = (const float*)d_in[5];
    const float* routed_w2 = (const float*)d_in[6];
    const float* router_w  = (const float*)d_in[7];
    const float* router_b  = (const float*)d_in[8];
    float* out = (float*)d_out;

    char* ws = (char*)d_ws;
    size_t off = 0;
    unsigned short* A     = (unsigned short*)(ws + off); off += (size_t)TOKENS * KPAD * 2;
    unsigned short* WcatT = (unsigned short*)(ws + off); off += (size_t)DOUT * KPAD * 2;
    unsigned short* W1T   = (unsigned short*)(ws + off); off += (size_t)NLOW * DIN * 2;
    float* H              = (float*)(ws + off);          off += (size_t)2 * TOKENS * NLOW * 4;
    float* cw             = (float*)(ws + off);          off += (size_t)TOKENS * NEXP * 4;

    prep_w2t<<<dim3(KPAD / 32, DOUT / 32), dim3(32, 8), 0, stream>>>(
        base_w, shared_w2, routed_w2, WcatT);
    prep_w1t<<<dim3(DIN / 32, NLOW / 32), dim3(32, 8), 0, stream>>>(
        shared_w1, routed_w1, W1T);
    router_kernel<<<TOKENS / 8, 256, 0, stream>>>(x, router_w, router_b, A, cw);
    gemm_small<<<dim3(1, TOKENS / 128, 2), 256, 0, stream>>>(A, W1T, H);
    combine_kernel<<<(TOKENS * 112) / 256, 256, 0, stream>>>(H, cw, A);
    gemm256<<<(TOKENS / 256) * (DOUT / 256), 512, 0, stream>>>(
        A, WcatT, base_b, out);
}